// Round 1
// baseline (3582.570 us; speedup 1.0000x reference)
//
#include <hip/hip_runtime.h>
#include <stdint.h>

// Problem dims (fixed)
#define H_DIM   4096
#define FF_DIM  14336
#define M_TOK   8192     // B*S = 4*2048
#define MT_CNT  64       // M tiles of 128

typedef __attribute__((ext_vector_type(8))) short  bf16x8;  // 8 bf16 (4 VGPRs)
typedef __attribute__((ext_vector_type(4))) float  f32x4;
typedef __attribute__((ext_vector_type(4))) int    i32x4;

// f32 -> bf16, round-to-nearest-even via bit trick
__device__ __forceinline__ unsigned short f2bf(float f) {
    union { float f; uint32_t u; } v; v.f = f;
    uint32_t r = v.u + 0x7FFFu + ((v.u >> 16) & 1u);
    return (unsigned short)(r >> 16);
}

// ternary int32 {-1,0,1} -> exact bf16 bits (no cvt chain)
__device__ __forceinline__ unsigned short t2bf(int v) {
    unsigned int mag = (v & 1) ? 0x3F80u : 0u;          // |v| ? 1.0 : 0.0
    unsigned int sgn = ((unsigned int)v >> 16) & 0x8000u; // sign of -1
    return (unsigned short)(mag | sgn);
}

__device__ __forceinline__ bf16x8 pack_f8(f32x4 a, f32x4 b) {
    bf16x8 o;
    o[0]=(short)f2bf(a[0]); o[1]=(short)f2bf(a[1]); o[2]=(short)f2bf(a[2]); o[3]=(short)f2bf(a[3]);
    o[4]=(short)f2bf(b[0]); o[5]=(short)f2bf(b[1]); o[6]=(short)f2bf(b[2]); o[7]=(short)f2bf(b[3]);
    return o;
}
__device__ __forceinline__ bf16x8 pack_t8(i32x4 a, i32x4 b) {
    bf16x8 o;
    o[0]=(short)t2bf(a[0]); o[1]=(short)t2bf(a[1]); o[2]=(short)t2bf(a[2]); o[3]=(short)t2bf(a[3]);
    o[4]=(short)t2bf(b[0]); o[5]=(short)t2bf(b[1]); o[6]=(short)t2bf(b[2]); o[7]=(short)t2bf(b[3]);
    return o;
}

// async global->LDS, 16B per lane (dest must be wave-uniform base + lane*16)
#define GLDS16(gp, lp) __builtin_amdgcn_global_load_lds( \
    (__attribute__((address_space(1))) void*)(gp),       \
    (__attribute__((address_space(3))) void*)(lp), 16, 0, 0)

// ---------------- conversion kernels ----------------
__global__ void k_cvt_f32(const float* __restrict__ in, unsigned short* __restrict__ out, int n8) {
    int i = blockIdx.x * blockDim.x + threadIdx.x;
    int stride = gridDim.x * blockDim.x;
    for (; i < n8; i += stride) {
        const f32x4* p = (const f32x4*)(in + (size_t)i * 8);
        *(bf16x8*)(out + (size_t)i * 8) = pack_f8(p[0], p[1]);
    }
}
__global__ void k_cvt_i32(const int* __restrict__ in, unsigned short* __restrict__ out, int n8) {
    int i = blockIdx.x * blockDim.x + threadIdx.x;
    int stride = gridDim.x * blockDim.x;
    for (; i < n8; i += stride) {
        const i32x4* p = (const i32x4*)(in + (size_t)i * 8);
        *(bf16x8*)(out + (size_t)i * 8) = pack_t8(p[0], p[1]);
    }
}

// ---------------- GEMM1: hidden = silu(x@gate^T * gs) * (x@up^T * us) ----------------
// 128x128 tile, BK=32, 4 waves (2x2), each wave 64x64 via 4x4 16x16x32 MFMA frags.
template<bool PREA, bool PREW>
__global__ __launch_bounds__(256, 2)
void k_gemm1(const float* __restrict__ xf, const unsigned short* __restrict__ xb,
             const int* __restrict__ gt, const int* __restrict__ ut,
             const unsigned short* __restrict__ gb, const unsigned short* __restrict__ ub,
             const float* __restrict__ gs, const float* __restrict__ us,
             unsigned short* __restrict__ hid)
{
    __shared__ unsigned short As[128][32];
    __shared__ unsigned short Gs[128][32];
    __shared__ unsigned short Us[128][32];

    const int tid  = threadIdx.x;
    const int lane = tid & 63;
    const int wv   = tid >> 6;
    const int wr   = wv >> 1;         // wave row (0..1)
    const int wc   = wv & 1;          // wave col (0..1)
    const int l15  = lane & 15;
    const int lq   = lane >> 4;

    // M-fastest block remap: co-resident blocks share the same weight panel
    const int bid = blockIdx.x;
    const int bm0 = (bid & (MT_CNT - 1)) * 128;
    const int bn0 = (bid >> 6) * 128;

    f32x4 accg[4][4] = {};
    f32x4 accu[4][4] = {};

    const int srow = tid >> 2;          // glds: 4 threads/row, rows 0..63 (+64 second issue)
    const int sseg = (tid & 3) * 8;     //       8 bf16 = 16B per lane
    const int crow = tid >> 1;          // reg-stage: 2 threads/row, 16 elems each
    const int ccol = (tid & 1) * 16;

    for (int k0 = 0; k0 < H_DIM; k0 += 32) {
        __syncthreads();   // previous iter's LDS reads done before overwrite
        if constexpr (PREA) {
            GLDS16(xb + (size_t)(bm0 + srow) * H_DIM + k0 + sseg,      &As[srow][sseg]);
            GLDS16(xb + (size_t)(bm0 + 64 + srow) * H_DIM + k0 + sseg, &As[64 + srow][sseg]);
        } else {
            const float* xa = xf + (size_t)(bm0 + crow) * H_DIM + k0 + ccol;
            f32x4 a0 = ((const f32x4*)xa)[0], a1 = ((const f32x4*)xa)[1];
            f32x4 a2 = ((const f32x4*)xa)[2], a3 = ((const f32x4*)xa)[3];
            *(bf16x8*)&As[crow][ccol]     = pack_f8(a0, a1);
            *(bf16x8*)&As[crow][ccol + 8] = pack_f8(a2, a3);
        }
        if constexpr (PREW) {
            const size_t w0 = (size_t)(bn0 + srow) * H_DIM + k0 + sseg;
            const size_t w1 = (size_t)(bn0 + 64 + srow) * H_DIM + k0 + sseg;
            GLDS16(gb + w0, &Gs[srow][sseg]);
            GLDS16(gb + w1, &Gs[64 + srow][sseg]);
            GLDS16(ub + w0, &Us[srow][sseg]);
            GLDS16(ub + w1, &Us[64 + srow][sseg]);
        } else {
            const size_t wo = (size_t)(bn0 + crow) * H_DIM + k0 + ccol;
            const i32x4* gp = (const i32x4*)(gt + wo);
            i32x4 g0 = gp[0], g1 = gp[1], g2 = gp[2], g3 = gp[3];
            *(bf16x8*)&Gs[crow][ccol]     = pack_t8(g0, g1);
            *(bf16x8*)&Gs[crow][ccol + 8] = pack_t8(g2, g3);
            const i32x4* up = (const i32x4*)(ut + wo);
            i32x4 u0 = up[0], u1 = up[1], u2 = up[2], u3 = up[3];
            *(bf16x8*)&Us[crow][ccol]     = pack_t8(u0, u1);
            *(bf16x8*)&Us[crow][ccol + 8] = pack_t8(u2, u3);
        }
        __syncthreads();

        bf16x8 af[4], gf[4], uf[4];
        #pragma unroll
        for (int m = 0; m < 4; m++)
            af[m] = *(const bf16x8*)&As[wr * 64 + m * 16 + l15][lq * 8];
        #pragma unroll
        for (int n = 0; n < 4; n++) {
            gf[n] = *(const bf16x8*)&Gs[wc * 64 + n * 16 + l15][lq * 8];
            uf[n] = *(const bf16x8*)&Us[wc * 64 + n * 16 + l15][lq * 8];
        }
        #pragma unroll
        for (int m = 0; m < 4; m++) {
            #pragma unroll
            for (int n = 0; n < 4; n++) {
                accg[m][n] = __builtin_amdgcn_mfma_f32_16x16x32_bf16(af[m], gf[n], accg[m][n], 0, 0, 0);
                accu[m][n] = __builtin_amdgcn_mfma_f32_16x16x32_bf16(af[m], uf[n], accu[m][n], 0, 0, 0);
            }
        }
    }

    // epilogue: scale, silu(g)*u, store bf16 hidden
    #pragma unroll
    for (int n = 0; n < 4; n++) {
        const int gcol = bn0 + wc * 64 + n * 16 + l15;
        const float sg = gs[gcol];
        const float su = us[gcol];
        #pragma unroll
        for (int m = 0; m < 4; m++) {
            const int grow = bm0 + wr * 64 + m * 16 + lq * 4;
            #pragma unroll
            for (int r = 0; r < 4; r++) {
                float g = accg[m][n][r] * sg;
                float u = accu[m][n][r] * su;
                float hv = g * (1.0f / (1.0f + __expf(-g))) * u;
                hid[(size_t)(grow + r) * FF_DIM + gcol] = f2bf(hv);
            }
        }
    }
}

// ---------------- GEMM2: out = (hidden @ down^T) * ds ----------------
template<bool PREW>
__global__ __launch_bounds__(256, 2)
void k_gemm2(const unsigned short* __restrict__ hid,
             const int* __restrict__ dt, const unsigned short* __restrict__ db,
             const float* __restrict__ dsc, float* __restrict__ out)
{
    __shared__ unsigned short As[128][32];
    __shared__ unsigned short Bs[128][32];

    const int tid  = threadIdx.x;
    const int lane = tid & 63;
    const int wv   = tid >> 6;
    const int wr   = wv >> 1;
    const int wc   = wv & 1;
    const int l15  = lane & 15;
    const int lq   = lane >> 4;

    const int bid = blockIdx.x;
    const int bm0 = (bid & (MT_CNT - 1)) * 128;
    const int bn0 = (bid >> 6) * 128;

    f32x4 acc[4][4] = {};

    const int srow = tid >> 2;
    const int sseg = (tid & 3) * 8;
    const int crow = tid >> 1;
    const int ccol = (tid & 1) * 16;

    for (int k0 = 0; k0 < FF_DIM; k0 += 32) {
        __syncthreads();
        GLDS16(hid + (size_t)(bm0 + srow) * FF_DIM + k0 + sseg,      &As[srow][sseg]);
        GLDS16(hid + (size_t)(bm0 + 64 + srow) * FF_DIM + k0 + sseg, &As[64 + srow][sseg]);
        if constexpr (PREW) {
            GLDS16(db + (size_t)(bn0 + srow) * FF_DIM + k0 + sseg,      &Bs[srow][sseg]);
            GLDS16(db + (size_t)(bn0 + 64 + srow) * FF_DIM + k0 + sseg, &Bs[64 + srow][sseg]);
        } else {
            const i32x4* dp = (const i32x4*)(dt + (size_t)(bn0 + crow) * FF_DIM + k0 + ccol);
            i32x4 d0 = dp[0], d1 = dp[1], d2 = dp[2], d3 = dp[3];
            *(bf16x8*)&Bs[crow][ccol]     = pack_t8(d0, d1);
            *(bf16x8*)&Bs[crow][ccol + 8] = pack_t8(d2, d3);
        }
        __syncthreads();

        bf16x8 af[4], bfr[4];
        #pragma unroll
        for (int m = 0; m < 4; m++)
            af[m] = *(const bf16x8*)&As[wr * 64 + m * 16 + l15][lq * 8];
        #pragma unroll
        for (int n = 0; n < 4; n++)
            bfr[n] = *(const bf16x8*)&Bs[wc * 64 + n * 16 + l15][lq * 8];
        #pragma unroll
        for (int m = 0; m < 4; m++) {
            #pragma unroll
            for (int n = 0; n < 4; n++)
                acc[m][n] = __builtin_amdgcn_mfma_f32_16x16x32_bf16(af[m], bfr[n], acc[m][n], 0, 0, 0);
        }
    }

    #pragma unroll
    for (int n = 0; n < 4; n++) {
        const int gcol = bn0 + wc * 64 + n * 16 + l15;
        const float sd = dsc[gcol];
        #pragma unroll
        for (int m = 0; m < 4; m++) {
            const int grow = bm0 + wr * 64 + m * 16 + lq * 4;
            #pragma unroll
            for (int r = 0; r < 4; r++)
                out[(size_t)(grow + r) * H_DIM + gcol] = acc[m][n][r] * sd;
        }
    }
}

extern "C" void kernel_launch(void* const* d_in, const int* in_sizes, int n_in,
                              void* d_out, int out_size, void* d_ws, size_t ws_size,
                              hipStream_t stream) {
    const float* xf  = (const float*)d_in[0];
    const int*   gt  = (const int*)d_in[1];
    const int*   ut  = (const int*)d_in[2];
    const int*   dt  = (const int*)d_in[3];
    const float* gsc = (const float*)d_in[4];
    const float* usc = (const float*)d_in[5];
    const float* dsc = (const float*)d_in[6];
    float* out = (float*)d_out;

    const size_t HID_B = (size_t)M_TOK * FF_DIM * 2;   // 224 MiB hidden bf16
    const size_t XB_B  = (size_t)M_TOK * H_DIM * 2;    // 64 MiB  x bf16
    const size_t W_B   = (size_t)FF_DIM * H_DIM * 2;   // 112 MiB per weight bf16

    unsigned short* hid = (unsigned short*)d_ws;
    unsigned short* xbp = (unsigned short*)((char*)d_ws + HID_B);
    unsigned short* gbp = (unsigned short*)((char*)d_ws + HID_B + XB_B);
    unsigned short* ubp = gbp + (size_t)FF_DIM * H_DIM;
    unsigned short* dbp = ubp + (size_t)FF_DIM * H_DIM;

    const bool has_xb = ws_size >= HID_B + XB_B;
    const bool has_w  = ws_size >= HID_B + XB_B + 3 * W_B;

    dim3 blk(256);
    const int n8x = (int)((size_t)M_TOK * H_DIM / 8);    // 4,194,304
    const int n8w = (int)((size_t)FF_DIM * H_DIM / 8);   // 7,340,032

    if (has_xb) k_cvt_f32<<<1024, blk, 0, stream>>>(xf, xbp, n8x);
    if (has_w) {
        k_cvt_i32<<<2048, blk, 0, stream>>>(gt, gbp, n8w);
        k_cvt_i32<<<2048, blk, 0, stream>>>(ut, ubp, n8w);
        k_cvt_i32<<<2048, blk, 0, stream>>>(dt, dbp, n8w);
    }

    const int grid1 = (FF_DIM / 128) * MT_CNT;  // 112*64 = 7168
    const int grid2 = (H_DIM / 128) * MT_CNT;   // 32*64  = 2048

    if (has_w)
        k_gemm1<true, true><<<grid1, blk, 0, stream>>>(nullptr, xbp, nullptr, nullptr,
                                                       gbp, ubp, gsc, usc, hid);
    else if (has_xb)
        k_gemm1<true, false><<<grid1, blk, 0, stream>>>(nullptr, xbp, gt, ut,
                                                        nullptr, nullptr, gsc, usc, hid);
    else
        k_gemm1<false, false><<<grid1, blk, 0, stream>>>(xf, nullptr, gt, ut,
                                                         nullptr, nullptr, gsc, usc, hid);

    if (has_w)
        k_gemm2<true><<<grid2, blk, 0, stream>>>(hid, nullptr, dbp, dsc, out);
    else
        k_gemm2<false><<<grid2, blk, 0, stream>>>(hid, dt, nullptr, dsc, out);
}

// Round 2
// 2997.929 us; speedup vs baseline: 1.1950x; 1.1950x over previous
//
#include <hip/hip_runtime.h>
#include <stdint.h>

// Problem dims (fixed)
#define H_DIM   4096
#define FF_DIM  14336
#define M_TOK   8192     // B*S = 4*2048
#define MT_CNT  64       // M tiles of 128
#define KC1     (H_DIM / 32)    // 128 k-chunks for K=H
#define KC2     (FF_DIM / 32)   // 448 k-chunks for K=FF

typedef __attribute__((ext_vector_type(8))) short  bf16x8;  // 8 bf16 (4 VGPRs)
typedef __attribute__((ext_vector_type(4))) float  f32x4;
typedef __attribute__((ext_vector_type(4))) int    i32x4;

// ---------- scalar converters ----------
__device__ __forceinline__ unsigned short f2bf(float f) {
    union { float f; uint32_t u; } v; v.f = f;
    uint32_t r = v.u + 0x7FFFu + ((v.u >> 16) & 1u);
    return (unsigned short)(r >> 16);
}
// ternary int32 {-1,0,1} -> exact bf16 bits
__device__ __forceinline__ unsigned short t2bf(int v) {
    unsigned int mag = (v & 1) ? 0x3F80u : 0u;
    unsigned int sgn = ((unsigned int)v >> 16) & 0x8000u;
    return (unsigned short)(mag | sgn);
}
__device__ __forceinline__ bf16x8 pack_f8(f32x4 a, f32x4 b) {
    bf16x8 o;
    o[0]=(short)f2bf(a[0]); o[1]=(short)f2bf(a[1]); o[2]=(short)f2bf(a[2]); o[3]=(short)f2bf(a[3]);
    o[4]=(short)f2bf(b[0]); o[5]=(short)f2bf(b[1]); o[6]=(short)f2bf(b[2]); o[7]=(short)f2bf(b[3]);
    return o;
}
__device__ __forceinline__ bf16x8 pack_t8(i32x4 a, i32x4 b) {
    bf16x8 o;
    o[0]=(short)t2bf(a[0]); o[1]=(short)t2bf(a[1]); o[2]=(short)t2bf(a[2]); o[3]=(short)t2bf(a[3]);
    o[4]=(short)t2bf(b[0]); o[5]=(short)t2bf(b[1]); o[6]=(short)t2bf(b[2]); o[7]=(short)t2bf(b[3]);
    return o;
}

// async global->LDS, 16B per lane (dest = wave-uniform base + lane*16)
#define GLDS16(gp, lp) __builtin_amdgcn_global_load_lds( \
    (__attribute__((address_space(1))) void*)(gp),       \
    (__attribute__((address_space(3))) void*)(lp), 16, 0, 0)

// =====================================================================
// Fragment-order layout for a row-major [R][K] matrix (bf16):
//   t = row/128, c = k/32, f = (row%128)/16,
//   l = (row%16) + ((k%32)/8)*16, e = k%8
//   flat = ((t*(K/32) + c)*8 + f)*512 + l*8 + e
// Per (t,c): 4096 ushorts = 8 KiB, staged linearly; ds_read_b128 at
// frag*1024 + lane*16 bytes -> conflict-free.
// =====================================================================

// output-linear converters: thread i produces out[i*8 .. i*8+8)
template<int K>
__global__ void k_cvt_f32_frag(const float* __restrict__ in,
                               unsigned short* __restrict__ out, int n8) {
    constexpr int KC = K / 32;
    int i = blockIdx.x * blockDim.x + threadIdx.x;
    int stride = gridDim.x * blockDim.x;
    for (; i < n8; i += stride) {
        int l = i & 63;
        int rest = i >> 6;
        int f = rest & 7;
        int rest2 = rest >> 3;
        int c = rest2 % KC;
        int t = rest2 / KC;
        int row = t * 128 + f * 16 + (l & 15);
        int k   = c * 32 + (l >> 4) * 8;
        const f32x4* p = (const f32x4*)(in + (size_t)row * K + k);
        *(bf16x8*)(out + (size_t)i * 8) = pack_f8(p[0], p[1]);
    }
}
template<int K>
__global__ void k_cvt_i32_frag(const int* __restrict__ in,
                               unsigned short* __restrict__ out, int n8) {
    constexpr int KC = K / 32;
    int i = blockIdx.x * blockDim.x + threadIdx.x;
    int stride = gridDim.x * blockDim.x;
    for (; i < n8; i += stride) {
        int l = i & 63;
        int rest = i >> 6;
        int f = rest & 7;
        int rest2 = rest >> 3;
        int c = rest2 % KC;
        int t = rest2 / KC;
        int row = t * 128 + f * 16 + (l & 15);
        int k   = c * 32 + (l >> 4) * 8;
        const i32x4* p = (const i32x4*)(in + (size_t)row * K + k);
        *(bf16x8*)(out + (size_t)i * 8) = pack_t8(p[0], p[1]);
    }
}

// reg-stage fallback: write a 16-element row-chunk into frag-order LDS
__device__ __forceinline__ void ds_write_frag(unsigned short* buf, int crow, int ccol,
                                              bf16x8 lo, bf16x8 hi) {
    int f  = crow >> 4;
    int la = (crow & 15) + (((ccol)     & 31) >> 3) * 16;
    int lb = (crow & 15) + (((ccol + 8) & 31) >> 3) * 16;
    *(bf16x8*)&buf[f * 512 + la * 8] = lo;
    *(bf16x8*)&buf[f * 512 + lb * 8] = hi;
}

// ---------------- GEMM1: hidden = silu(x@gate^T * gs) * (x@up^T * us) ----------------
// 128x128 tile, BK=32, 4 waves (2x2), each wave 64x64 via 4x4 16x16x32 MFMA frags.
template<bool PREA, bool PREW>
__global__ __launch_bounds__(256, 2)
void k_gemm1(const float* __restrict__ xf, const unsigned short* __restrict__ xb,
             const int* __restrict__ gt, const int* __restrict__ ut,
             const unsigned short* __restrict__ gb, const unsigned short* __restrict__ ub,
             const float* __restrict__ gs, const float* __restrict__ us,
             unsigned short* __restrict__ hid)
{
    __shared__ unsigned short As[4096];
    __shared__ unsigned short Gs[4096];
    __shared__ unsigned short Us[4096];

    const int tid  = threadIdx.x;
    const int lane = tid & 63;
    const int wv   = tid >> 6;
    const int wr   = wv >> 1;         // wave row (0..1)
    const int wc   = wv & 1;          // wave col (0..1)
    const int l15  = lane & 15;
    const int lq   = lane >> 4;

    // M-fastest block remap: co-resident blocks share the same weight panel
    const int bid = blockIdx.x;
    const int bmt = bid & (MT_CNT - 1);     // m-tile 0..63
    const int bnt = bid >> 6;               // ff-tile 0..111
    const int bm0 = bmt * 128;
    const int bn0 = bnt * 128;

    f32x4 accg[4][4] = {};
    f32x4 accu[4][4] = {};

    // frag-order tile bases (advance 4096 ushorts per k-chunk)
    const unsigned short* pa = PREA ? xb + (size_t)bmt * KC1 * 4096 : nullptr;
    const unsigned short* pg = PREW ? gb + (size_t)bnt * KC1 * 4096 : nullptr;
    const unsigned short* pu = PREW ? ub + (size_t)bnt * KC1 * 4096 : nullptr;

    const int crow = tid >> 1;          // reg-stage: 2 threads/row, 16 elems each
    const int ccol = (tid & 1) * 16;

    for (int kc = 0; kc < KC1; kc++) {
        __syncthreads();   // previous iter's LDS reads done before overwrite
        const int k0 = kc * 32;
        if constexpr (PREA) {
            GLDS16(pa + tid * 8,        &As[tid * 8]);
            GLDS16(pa + tid * 8 + 2048, &As[tid * 8 + 2048]);
        } else {
            const float* xa = xf + (size_t)(bm0 + crow) * H_DIM + k0 + ccol;
            f32x4 a0 = ((const f32x4*)xa)[0], a1 = ((const f32x4*)xa)[1];
            f32x4 a2 = ((const f32x4*)xa)[2], a3 = ((const f32x4*)xa)[3];
            ds_write_frag(As, crow, ccol, pack_f8(a0, a1), pack_f8(a2, a3));
        }
        if constexpr (PREW) {
            GLDS16(pg + tid * 8,        &Gs[tid * 8]);
            GLDS16(pg + tid * 8 + 2048, &Gs[tid * 8 + 2048]);
            GLDS16(pu + tid * 8,        &Us[tid * 8]);
            GLDS16(pu + tid * 8 + 2048, &Us[tid * 8 + 2048]);
        } else {
            const size_t wo = (size_t)(bn0 + crow) * H_DIM + k0 + ccol;
            const i32x4* gp = (const i32x4*)(gt + wo);
            i32x4 g0 = gp[0], g1 = gp[1], g2 = gp[2], g3 = gp[3];
            ds_write_frag(Gs, crow, ccol, pack_t8(g0, g1), pack_t8(g2, g3));
            const i32x4* up = (const i32x4*)(ut + wo);
            i32x4 u0 = up[0], u1 = up[1], u2 = up[2], u3 = up[3];
            ds_write_frag(Us, crow, ccol, pack_t8(u0, u1), pack_t8(u2, u3));
        }
        __syncthreads();

        bf16x8 af[4], gf[4], uf[4];
        #pragma unroll
        for (int m = 0; m < 4; m++)
            af[m] = *(const bf16x8*)&As[(wr * 4 + m) * 512 + lane * 8];
        #pragma unroll
        for (int n = 0; n < 4; n++) {
            gf[n] = *(const bf16x8*)&Gs[(wc * 4 + n) * 512 + lane * 8];
            uf[n] = *(const bf16x8*)&Us[(wc * 4 + n) * 512 + lane * 8];
        }
        #pragma unroll
        for (int m = 0; m < 4; m++) {
            #pragma unroll
            for (int n = 0; n < 4; n++) {
                accg[m][n] = __builtin_amdgcn_mfma_f32_16x16x32_bf16(af[m], gf[n], accg[m][n], 0, 0, 0);
                accu[m][n] = __builtin_amdgcn_mfma_f32_16x16x32_bf16(af[m], uf[n], accu[m][n], 0, 0, 0);
            }
        }
        if constexpr (PREA) pa += 4096;
        if constexpr (PREW) { pg += 4096; pu += 4096; }
    }

    // epilogue: scale, silu(g)*u, store bf16 hidden in FRAG ORDER for gemm2's A
    #pragma unroll
    for (int n = 0; n < 4; n++) {
        const int gcol = bn0 + wc * 64 + n * 16 + l15;   // k index for gemm2
        const float sg = gs[gcol];
        const float su = us[gcol];
        const int c = gcol >> 5;
        const int lpart = ((gcol & 31) >> 3) * 16;
        const int e = gcol & 7;
        #pragma unroll
        for (int m = 0; m < 4; m++) {
            const int rb = bm0 + wr * 64 + m * 16 + lq * 4;
            #pragma unroll
            for (int r = 0; r < 4; r++) {
                const int row = rb + r;
                float g = accg[m][n][r] * sg;
                float u = accu[m][n][r] * su;
                float hv = g * (1.0f / (1.0f + __expf(-g))) * u;
                const int t = row >> 7;
                const int f = (row >> 4) & 7;
                const int l = (row & 15) + lpart;
                hid[(((size_t)t * KC2 + c) * 8 + f) * 512 + l * 8 + e] = f2bf(hv);
            }
        }
    }
}

// ---------------- GEMM2: out = (hidden @ down^T) * ds ----------------
template<bool PREW>
__global__ __launch_bounds__(256, 2)
void k_gemm2(const unsigned short* __restrict__ hid,
             const int* __restrict__ dt, const unsigned short* __restrict__ db,
             const float* __restrict__ dsc, float* __restrict__ out)
{
    __shared__ unsigned short As[4096];
    __shared__ unsigned short Bs[4096];

    const int tid  = threadIdx.x;
    const int lane = tid & 63;
    const int wv   = tid >> 6;
    const int wr   = wv >> 1;
    const int wc   = wv & 1;
    const int l15  = lane & 15;
    const int lq   = lane >> 4;

    const int bid = blockIdx.x;
    const int bmt = bid & (MT_CNT - 1);
    const int bnt = bid >> 6;               // 0..31
    const int bm0 = bmt * 128;
    const int bn0 = bnt * 128;

    f32x4 acc[4][4] = {};

    const unsigned short* pa = hid + (size_t)bmt * KC2 * 4096;
    const unsigned short* pb = PREW ? db + (size_t)bnt * KC2 * 4096 : nullptr;

    const int crow = tid >> 1;
    const int ccol = (tid & 1) * 16;

    for (int kc = 0; kc < KC2; kc++) {
        __syncthreads();
        GLDS16(pa + tid * 8,        &As[tid * 8]);
        GLDS16(pa + tid * 8 + 2048, &As[tid * 8 + 2048]);
        if constexpr (PREW) {
            GLDS16(pb + tid * 8,        &Bs[tid * 8]);
            GLDS16(pb + tid * 8 + 2048, &Bs[tid * 8 + 2048]);
        } else {
            const i32x4* dp = (const i32x4*)(dt + (size_t)(bn0 + crow) * FF_DIM + kc * 32 + ccol);
            i32x4 d0 = dp[0], d1 = dp[1], d2 = dp[2], d3 = dp[3];
            ds_write_frag(Bs, crow, ccol, pack_t8(d0, d1), pack_t8(d2, d3));
        }
        __syncthreads();

        bf16x8 af[4], bfr[4];
        #pragma unroll
        for (int m = 0; m < 4; m++)
            af[m] = *(const bf16x8*)&As[(wr * 4 + m) * 512 + lane * 8];
        #pragma unroll
        for (int n = 0; n < 4; n++)
            bfr[n] = *(const bf16x8*)&Bs[(wc * 4 + n) * 512 + lane * 8];
        #pragma unroll
        for (int m = 0; m < 4; m++) {
            #pragma unroll
            for (int n = 0; n < 4; n++)
                acc[m][n] = __builtin_amdgcn_mfma_f32_16x16x32_bf16(af[m], bfr[n], acc[m][n], 0, 0, 0);
        }
        pa += 4096;
        if constexpr (PREW) pb += 4096;
    }

    #pragma unroll
    for (int n = 0; n < 4; n++) {
        const int gcol = bn0 + wc * 64 + n * 16 + l15;
        const float sd = dsc[gcol];
        #pragma unroll
        for (int m = 0; m < 4; m++) {
            const int grow = bm0 + wr * 64 + m * 16 + lq * 4;
            #pragma unroll
            for (int r = 0; r < 4; r++)
                out[(size_t)(grow + r) * H_DIM + gcol] = acc[m][n][r] * sd;
        }
    }
}

extern "C" void kernel_launch(void* const* d_in, const int* in_sizes, int n_in,
                              void* d_out, int out_size, void* d_ws, size_t ws_size,
                              hipStream_t stream) {
    const float* xf  = (const float*)d_in[0];
    const int*   gt  = (const int*)d_in[1];
    const int*   ut  = (const int*)d_in[2];
    const int*   dt  = (const int*)d_in[3];
    const float* gsc = (const float*)d_in[4];
    const float* usc = (const float*)d_in[5];
    const float* dsc = (const float*)d_in[6];
    float* out = (float*)d_out;

    const size_t HID_B = (size_t)M_TOK * FF_DIM * 2;   // 224 MiB hidden bf16 (frag order)
    const size_t XB_B  = (size_t)M_TOK * H_DIM * 2;    // 64 MiB  x bf16 (frag order)
    const size_t W_B   = (size_t)FF_DIM * H_DIM * 2;   // 112 MiB per weight bf16 (frag order)

    unsigned short* hid = (unsigned short*)d_ws;
    unsigned short* xbp = (unsigned short*)((char*)d_ws + HID_B);
    unsigned short* gbp = (unsigned short*)((char*)d_ws + HID_B + XB_B);
    unsigned short* ubp = gbp + (size_t)FF_DIM * H_DIM;
    unsigned short* dbp = ubp + (size_t)FF_DIM * H_DIM;

    const bool has_xb = ws_size >= HID_B + XB_B;
    const bool has_w  = ws_size >= HID_B + XB_B + 3 * W_B;

    dim3 blk(256);
    const int n8x = (int)((size_t)M_TOK * H_DIM / 8);    // 4,194,304
    const int n8w = (int)((size_t)FF_DIM * H_DIM / 8);   // 7,340,032

    if (has_xb) k_cvt_f32_frag<H_DIM><<<1024, blk, 0, stream>>>(xf, xbp, n8x);
    if (has_w) {
        k_cvt_i32_frag<H_DIM><<<2048, blk, 0, stream>>>(gt, gbp, n8w);
        k_cvt_i32_frag<H_DIM><<<2048, blk, 0, stream>>>(ut, ubp, n8w);
        k_cvt_i32_frag<FF_DIM><<<2048, blk, 0, stream>>>(dt, dbp, n8w);
    }

    const int grid1 = (FF_DIM / 128) * MT_CNT;  // 112*64 = 7168
    const int grid2 = (H_DIM / 128) * MT_CNT;   // 32*64  = 2048

    if (has_w)
        k_gemm1<true, true><<<grid1, blk, 0, stream>>>(nullptr, xbp, nullptr, nullptr,
                                                       gbp, ubp, gsc, usc, hid);
    else if (has_xb)
        k_gemm1<true, false><<<grid1, blk, 0, stream>>>(nullptr, xbp, gt, ut,
                                                        nullptr, nullptr, gsc, usc, hid);
    else
        k_gemm1<false, false><<<grid1, blk, 0, stream>>>(xf, nullptr, gt, ut,
                                                         nullptr, nullptr, gsc, usc, hid);

    if (has_w)
        k_gemm2<true><<<grid2, blk, 0, stream>>>(hid, nullptr, dbp, dsc, out);
    else
        k_gemm2<false><<<grid2, blk, 0, stream>>>(hid, dt, nullptr, dsc, out);
}

// Round 3
// 2361.945 us; speedup vs baseline: 1.5168x; 1.2693x over previous
//
#include <hip/hip_runtime.h>
#include <stdint.h>

// Problem dims (fixed)
#define H_DIM   4096
#define FF_DIM  14336
#define M_TOK   8192     // B*S = 4*2048
#define KC1     (H_DIM / 32)    // 128 k-chunks (halves) for K=H
#define KC2     (FF_DIM / 32)   // 448 k-chunks (halves) for K=FF

typedef unsigned short ushort_t;
typedef __attribute__((ext_vector_type(8))) short  bf16x8;  // 8 bf16 (4 VGPRs)
typedef __attribute__((ext_vector_type(4))) float  f32x4;
typedef __attribute__((ext_vector_type(4))) int    i32x4;

// ---------- scalar converters ----------
__device__ __forceinline__ unsigned short f2bf(float f) {
    union { float f; uint32_t u; } v; v.f = f;
    uint32_t r = v.u + 0x7FFFu + ((v.u >> 16) & 1u);
    return (unsigned short)(r >> 16);
}
// ternary int32 {-1,0,1} -> exact bf16 bits
__device__ __forceinline__ unsigned short t2bf(int v) {
    unsigned int mag = (v & 1) ? 0x3F80u : 0u;
    unsigned int sgn = ((unsigned int)v >> 16) & 0x8000u;
    return (unsigned short)(mag | sgn);
}
__device__ __forceinline__ bf16x8 pack_f8(f32x4 a, f32x4 b) {
    bf16x8 o;
    o[0]=(short)f2bf(a[0]); o[1]=(short)f2bf(a[1]); o[2]=(short)f2bf(a[2]); o[3]=(short)f2bf(a[3]);
    o[4]=(short)f2bf(b[0]); o[5]=(short)f2bf(b[1]); o[6]=(short)f2bf(b[2]); o[7]=(short)f2bf(b[3]);
    return o;
}
__device__ __forceinline__ bf16x8 pack_t8(i32x4 a, i32x4 b) {
    bf16x8 o;
    o[0]=(short)t2bf(a[0]); o[1]=(short)t2bf(a[1]); o[2]=(short)t2bf(a[2]); o[3]=(short)t2bf(a[3]);
    o[4]=(short)t2bf(b[0]); o[5]=(short)t2bf(b[1]); o[6]=(short)t2bf(b[2]); o[7]=(short)t2bf(b[3]);
    return o;
}

// async global->LDS, 16B per lane (dest = wave-uniform base + lane*16)
#define GLDS16(gp, lp) __builtin_amdgcn_global_load_lds( \
    (__attribute__((address_space(1))) void*)(gp),       \
    (__attribute__((address_space(3))) void*)(lp), 16, 0, 0)

#define WAITVM8 asm volatile("s_waitcnt vmcnt(8)" ::: "memory")
#define WAITVM4 asm volatile("s_waitcnt vmcnt(4)" ::: "memory")
#define WAITVM0 asm volatile("s_waitcnt vmcnt(0)" ::: "memory")
#define SBAR    asm volatile("s_barrier" ::: "memory")

// =====================================================================
// Fragment-order layout for a row-major [R][K] matrix (bf16):
//   t = row/128, c = k/32, f = (row%128)/16,
//   l = (row%16) + ((k%32)/8)*16, e = k%8
//   flat = ((t*(K/32) + c)*8 + f)*512 + l*8 + e
// Per (t,c): 4096 ushorts = 8 KiB, staged linearly; ds_read_b128 at
// frag*1024 + lane*16 bytes -> conflict-free.
// =====================================================================

// ---------------- coalesced converters (LDS transpose) ----------------
// one block: rows [t*128, t*128+128) x k [cp*64, cp*64+64)
template<int K, bool TERN>
__global__ __launch_bounds__(256)
void k_cvt_lds(const void* __restrict__ inv, unsigned short* __restrict__ out) {
    constexpr int KC = K / 32;
    constexpr int CP = K / 64;
    __shared__ int sm[128][68];   // +4 pad: read-out is 2-way max
    const int b   = blockIdx.x;
    const int t   = b / CP;
    const int cp  = b % CP;
    const int tid = threadIdx.x;
    const int rr  = tid >> 4;          // 16 threads per row
    const int c4  = (tid & 15) * 4;    // 16B per thread
    const int k0  = cp * 64;

    const int* in = (const int*)inv;   // bit-copy works for f32 too
    #pragma unroll
    for (int p = 0; p < 8; ++p) {
        const int row = p * 16 + rr;
        *(i32x4*)&sm[row][c4] = *(const i32x4*)(in + (size_t)(t * 128 + row) * K + k0 + c4);
    }
    __syncthreads();
    #pragma unroll
    for (int p = 0; p < 4; ++p) {
        const int idx = p * 256 + tid;
        const int cc  = idx >> 9;         // 0..1
        const int f   = (idx >> 6) & 7;
        const int l   = idx & 63;
        const int row = f * 16 + (l & 15);
        const int kl  = cc * 32 + (l >> 4) * 8;
        bf16x8 o;
        if (TERN) {
            i32x4 a = *(const i32x4*)&sm[row][kl];
            i32x4 bq = *(const i32x4*)&sm[row][kl + 4];
            o = pack_t8(a, bq);
        } else {
            f32x4 a = *(const f32x4*)&sm[row][kl];
            f32x4 bq = *(const f32x4*)&sm[row][kl + 4];
            o = pack_f8(a, bq);
        }
        *(bf16x8*)(out + (((size_t)t * KC + (cp * 2 + cc)) * 8 + f) * 512 + (size_t)l * 8) = o;
    }
}

// ---------------- GEMM1 8-phase: hidden = silu(x@gate^T*gs)*(x@up^T*us) ----------------
// 256M x 128N tile, 8 waves (4Mx2N), BK=64 as 2 half-tiles of 32.
// LDS: 4 slots x 32KB (A 16KB = 2 chunks, G 8KB, U 8KB). Prefetch depth 3,
// counted vmcnt(8) (4 loads/half, 2 halves in flight after wait).
__global__ __launch_bounds__(512, 2)
void k_gemm1_8p(const ushort_t* __restrict__ xb,
                const ushort_t* __restrict__ gb, const ushort_t* __restrict__ ub,
                const float* __restrict__ gs, const float* __restrict__ us,
                ushort_t* __restrict__ hid)
{
    __shared__ ushort_t lds[65536];   // 128 KiB
    const int tid  = threadIdx.x;
    const int lane = tid & 63;
    const int wv   = tid >> 6;
    const int wr   = wv >> 1;          // 0..3 (M)
    const int wc   = wv & 1;           // 0..1 (N)
    const int l15  = lane & 15;
    const int lq   = lane >> 4;

    const int bid = blockIdx.x;
    const int bmt = bid & 31;          // 32 m-tiles of 256 (M-fastest: weight panels read once)
    const int bnt = bid >> 5;          // 112 n-tiles of 128

    const ushort_t* xa0 = xb + ((size_t)(bmt * 2)     * KC1) * 4096;
    const ushort_t* xa1 = xb + ((size_t)(bmt * 2 + 1) * KC1) * 4096;
    const ushort_t* gbb = gb + ((size_t)bnt * KC1) * 4096;
    const ushort_t* ubb = ub + ((size_t)bnt * KC1) * 4096;

    f32x4 accg[4][4] = {};
    f32x4 accu[4][4] = {};

    // prologue: stage halves 0,1,2 (issue order = retirement order)
    #pragma unroll
    for (int h = 0; h < 3; ++h) {
        ushort_t* sl = lds + h * 16384;
        GLDS16(xa0 + (size_t)h * 4096 + tid * 8, sl + tid * 8);
        GLDS16(xa1 + (size_t)h * 4096 + tid * 8, sl + 4096 + tid * 8);
        GLDS16(gbb + (size_t)h * 4096 + tid * 8, sl + 8192 + tid * 8);
        GLDS16(ubb + (size_t)h * 4096 + tid * 8, sl + 12288 + tid * 8);
    }

#define G1_HALF(WAITOP, DO_ISSUE)                                                  \
  {                                                                                \
    ushort_t* slot = lds + (H & 3) * 16384;                                        \
    const ushort_t* Ab = slot + (wr >> 1) * 4096 + ((wr & 1) * 4) * 512 + lane * 8;\
    const ushort_t* Gb = slot + 8192 + (wc * 4) * 512 + lane * 8;                  \
    const ushort_t* Ub = slot + 12288 + (wc * 4) * 512 + lane * 8;                 \
    WAITOP;                                                                        \
    SBAR;                                                                          \
    bf16x8 af[4], gf[4], uf[4];                                                    \
    _Pragma("unroll")                                                              \
    for (int m = 0; m < 4; m++) af[m] = *(const bf16x8*)(Ab + m * 512);            \
    _Pragma("unroll")                                                              \
    for (int n = 0; n < 4; n++) gf[n] = *(const bf16x8*)(Gb + n * 512);            \
    if (DO_ISSUE) {                                                                \
      const int Hp = H + 3;                                                        \
      ushort_t* sp = lds + (Hp & 3) * 16384;                                       \
      GLDS16(xa0 + (size_t)Hp * 4096 + tid * 8, sp + tid * 8);                     \
      GLDS16(xa1 + (size_t)Hp * 4096 + tid * 8, sp + 4096 + tid * 8);              \
    }                                                                              \
    __builtin_amdgcn_s_setprio(1);                                                 \
    _Pragma("unroll")                                                              \
    for (int m = 0; m < 4; m++)                                                    \
      _Pragma("unroll")                                                            \
      for (int n = 0; n < 4; n++)                                                  \
        accg[m][n] = __builtin_amdgcn_mfma_f32_16x16x32_bf16(af[m], gf[n], accg[m][n], 0, 0, 0); \
    __builtin_amdgcn_s_setprio(0);                                                 \
    SBAR;                                                                          \
    _Pragma("unroll")                                                              \
    for (int n = 0; n < 4; n++) uf[n] = *(const bf16x8*)(Ub + n * 512);            \
    if (DO_ISSUE) {                                                                \
      const int Hp = H + 3;                                                        \
      ushort_t* sp = lds + (Hp & 3) * 16384;                                       \
      GLDS16(gbb + (size_t)Hp * 4096 + tid * 8, sp + 8192 + tid * 8);              \
      GLDS16(ubb + (size_t)Hp * 4096 + tid * 8, sp + 12288 + tid * 8);             \
    }                                                                              \
    __builtin_amdgcn_s_setprio(1);                                                 \
    _Pragma("unroll")                                                              \
    for (int m = 0; m < 4; m++)                                                    \
      _Pragma("unroll")                                                            \
      for (int n = 0; n < 4; n++)                                                  \
        accu[m][n] = __builtin_amdgcn_mfma_f32_16x16x32_bf16(af[m], uf[n], accu[m][n], 0, 0, 0); \
    __builtin_amdgcn_s_setprio(0);                                                 \
  }

    int H = 0;
    for (; H < KC1 - 3; ++H) G1_HALF(WAITVM8, 1);
    G1_HALF(WAITVM8, 0); ++H;
    G1_HALF(WAITVM4, 0); ++H;
    G1_HALF(WAITVM0, 0);
#undef G1_HALF

    // epilogue: scale, silu(g)*u, store bf16 hidden in FRAG ORDER for gemm2's A
    const int bm0 = bmt * 256;
    const int bn0 = bnt * 128;
    #pragma unroll
    for (int n = 0; n < 4; n++) {
        const int gcol = bn0 + wc * 64 + n * 16 + l15;   // k index for gemm2
        const float sg = gs[gcol];
        const float su = us[gcol];
        const int c  = gcol >> 5;
        const int lp = ((gcol & 31) >> 3) * 16;
        const int e  = gcol & 7;
        #pragma unroll
        for (int m = 0; m < 4; m++) {
            const int rb = bm0 + wr * 64 + m * 16 + lq * 4;
            #pragma unroll
            for (int r = 0; r < 4; r++) {
                const int row = rb + r;
                float g = accg[m][n][r] * sg;
                float u = accu[m][n][r] * su;
                float hv = g * (1.0f / (1.0f + __expf(-g))) * u;
                const int t = row >> 7;
                const int f = (row >> 4) & 7;
                const int l = (row & 15) + lp;
                hid[(((size_t)t * KC2 + c) * 8 + f) * 512 + l * 8 + e] = f2bf(hv);
            }
        }
    }
}

// ---------------- GEMM2 8-phase: out = (hidden @ down^T) * ds ----------------
// 256M x 256N tile, 8 waves (2Mx4N). LDS: 4 slots x 32KB (A 16KB, B 16KB).
__global__ __launch_bounds__(512, 2)
void k_gemm2_8p(const ushort_t* __restrict__ hid, const ushort_t* __restrict__ db,
                const float* __restrict__ dsc, float* __restrict__ out)
{
    __shared__ ushort_t lds[65536];
    const int tid  = threadIdx.x;
    const int lane = tid & 63;
    const int wv   = tid >> 6;
    const int wr   = wv >> 2;          // 0..1 (M: 128 rows each)
    const int wc   = wv & 3;           // 0..3 (N: 64 cols each)
    const int l15  = lane & 15;
    const int lq   = lane >> 4;

    const int bid = blockIdx.x;
    const int bmt = bid & 31;          // 32 m-tiles of 256
    const int bnt = bid >> 5;          // 16 n-tiles of 256

    const ushort_t* ha0 = hid + ((size_t)(bmt * 2)     * KC2) * 4096;
    const ushort_t* ha1 = hid + ((size_t)(bmt * 2 + 1) * KC2) * 4096;
    const ushort_t* db0 = db  + ((size_t)(bnt * 2)     * KC2) * 4096;
    const ushort_t* db1 = db  + ((size_t)(bnt * 2 + 1) * KC2) * 4096;

    f32x4 acc[8][4] = {};

    #pragma unroll
    for (int h = 0; h < 3; ++h) {
        ushort_t* sl = lds + h * 16384;
        GLDS16(ha0 + (size_t)h * 4096 + tid * 8, sl + tid * 8);
        GLDS16(ha1 + (size_t)h * 4096 + tid * 8, sl + 4096 + tid * 8);
        GLDS16(db0 + (size_t)h * 4096 + tid * 8, sl + 8192 + tid * 8);
        GLDS16(db1 + (size_t)h * 4096 + tid * 8, sl + 12288 + tid * 8);
    }

#define G2_HALF(WAITOP, DO_ISSUE)                                                  \
  {                                                                                \
    ushort_t* slot = lds + (H & 3) * 16384;                                        \
    const ushort_t* Ab = slot + wr * 4096 + lane * 8;                              \
    const ushort_t* Bb = slot + 8192 + (wc >> 1) * 4096 + ((wc & 1) * 4) * 512 + lane * 8; \
    WAITOP;                                                                        \
    SBAR;                                                                          \
    bf16x8 af[4], bfv[4];                                                          \
    _Pragma("unroll")                                                              \
    for (int m = 0; m < 4; m++) af[m] = *(const bf16x8*)(Ab + m * 512);            \
    _Pragma("unroll")                                                              \
    for (int n = 0; n < 4; n++) bfv[n] = *(const bf16x8*)(Bb + n * 512);           \
    if (DO_ISSUE) {                                                                \
      const int Hp = H + 3;                                                        \
      ushort_t* sp = lds + (Hp & 3) * 16384;                                       \
      GLDS16(ha0 + (size_t)Hp * 4096 + tid * 8, sp + tid * 8);                     \
      GLDS16(ha1 + (size_t)Hp * 4096 + tid * 8, sp + 4096 + tid * 8);              \
    }                                                                              \
    __builtin_amdgcn_s_setprio(1);                                                 \
    _Pragma("unroll")                                                              \
    for (int m = 0; m < 4; m++)                                                    \
      _Pragma("unroll")                                                            \
      for (int n = 0; n < 4; n++)                                                  \
        acc[m][n] = __builtin_amdgcn_mfma_f32_16x16x32_bf16(af[m], bfv[n], acc[m][n], 0, 0, 0); \
    __builtin_amdgcn_s_setprio(0);                                                 \
    SBAR;                                                                          \
    bf16x8 af2[4];                                                                 \
    _Pragma("unroll")                                                              \
    for (int m = 0; m < 4; m++) af2[m] = *(const bf16x8*)(Ab + (4 + m) * 512);     \
    if (DO_ISSUE) {                                                                \
      const int Hp = H + 3;                                                        \
      ushort_t* sp = lds + (Hp & 3) * 16384;                                       \
      GLDS16(db0 + (size_t)Hp * 4096 + tid * 8, sp + 8192 + tid * 8);              \
      GLDS16(db1 + (size_t)Hp * 4096 + tid * 8, sp + 12288 + tid * 8);             \
    }                                                                              \
    __builtin_amdgcn_s_setprio(1);                                                 \
    _Pragma("unroll")                                                              \
    for (int m = 0; m < 4; m++)                                                    \
      _Pragma("unroll")                                                            \
      for (int n = 0; n < 4; n++)                                                  \
        acc[4 + m][n] = __builtin_amdgcn_mfma_f32_16x16x32_bf16(af2[m], bfv[n], acc[4 + m][n], 0, 0, 0); \
    __builtin_amdgcn_s_setprio(0);                                                 \
  }

    int H = 0;
    for (; H < KC2 - 3; ++H) G2_HALF(WAITVM8, 1);
    G2_HALF(WAITVM8, 0); ++H;
    G2_HALF(WAITVM4, 0); ++H;
    G2_HALF(WAITVM0, 0);
#undef G2_HALF

    const int bm0 = bmt * 256;
    const int bn0 = bnt * 256;
    #pragma unroll
    for (int n = 0; n < 4; n++) {
        const int gcol = bn0 + wc * 64 + n * 16 + l15;
        const float sd = dsc[gcol];
        #pragma unroll
        for (int m = 0; m < 8; m++) {
            const int grow = bm0 + wr * 128 + m * 16 + lq * 4;
            #pragma unroll
            for (int r = 0; r < 4; r++)
                out[(size_t)(grow + r) * H_DIM + gcol] = acc[m][n][r] * sd;
        }
    }
}

// ================= fallback (small ws) — R2 structure, known good =================
__device__ __forceinline__ void ds_write_frag(ushort_t* buf, int crow, int ccol,
                                              bf16x8 lo, bf16x8 hi) {
    int f  = crow >> 4;
    int la = (crow & 15) + (((ccol)     & 31) >> 3) * 16;
    int lb = (crow & 15) + (((ccol + 8) & 31) >> 3) * 16;
    *(bf16x8*)&buf[f * 512 + la * 8] = lo;
    *(bf16x8*)&buf[f * 512 + lb * 8] = hi;
}

template<bool PREA>
__global__ __launch_bounds__(256, 2)
void k_gemm1_fb(const float* __restrict__ xf, const ushort_t* __restrict__ xb,
                const int* __restrict__ gt, const int* __restrict__ ut,
                const float* __restrict__ gs, const float* __restrict__ us,
                ushort_t* __restrict__ hid)
{
    __shared__ ushort_t As[4096];
    __shared__ ushort_t Gs[4096];
    __shared__ ushort_t Us[4096];

    const int tid  = threadIdx.x;
    const int lane = tid & 63;
    const int wv   = tid >> 6;
    const int wr   = wv >> 1;
    const int wc   = wv & 1;
    const int l15  = lane & 15;
    const int lq   = lane >> 4;

    const int bid = blockIdx.x;
    const int bmt = bid & 63;
    const int bnt = bid >> 6;
    const int bm0 = bmt * 128;
    const int bn0 = bnt * 128;

    f32x4 accg[4][4] = {};
    f32x4 accu[4][4] = {};

    const ushort_t* pa = PREA ? xb + (size_t)bmt * KC1 * 4096 : nullptr;
    const int crow = tid >> 1;
    const int ccol = (tid & 1) * 16;

    for (int kc = 0; kc < KC1; kc++) {
        __syncthreads();
        const int k0 = kc * 32;
        if constexpr (PREA) {
            GLDS16(pa + tid * 8,        &As[tid * 8]);
            GLDS16(pa + tid * 8 + 2048, &As[tid * 8 + 2048]);
        } else {
            const float* xa = xf + (size_t)(bm0 + crow) * H_DIM + k0 + ccol;
            f32x4 a0 = ((const f32x4*)xa)[0], a1 = ((const f32x4*)xa)[1];
            f32x4 a2 = ((const f32x4*)xa)[2], a3 = ((const f32x4*)xa)[3];
            ds_write_frag(As, crow, ccol, pack_f8(a0, a1), pack_f8(a2, a3));
        }
        {
            const size_t wo = (size_t)(bn0 + crow) * H_DIM + k0 + ccol;
            const i32x4* gp = (const i32x4*)(gt + wo);
            i32x4 g0 = gp[0], g1 = gp[1], g2 = gp[2], g3 = gp[3];
            ds_write_frag(Gs, crow, ccol, pack_t8(g0, g1), pack_t8(g2, g3));
            const i32x4* up = (const i32x4*)(ut + wo);
            i32x4 u0 = up[0], u1 = up[1], u2 = up[2], u3 = up[3];
            ds_write_frag(Us, crow, ccol, pack_t8(u0, u1), pack_t8(u2, u3));
        }
        __syncthreads();

        bf16x8 af[4], gf[4], uf[4];
        #pragma unroll
        for (int m = 0; m < 4; m++)
            af[m] = *(const bf16x8*)&As[(wr * 4 + m) * 512 + lane * 8];
        #pragma unroll
        for (int n = 0; n < 4; n++) {
            gf[n] = *(const bf16x8*)&Gs[(wc * 4 + n) * 512 + lane * 8];
            uf[n] = *(const bf16x8*)&Us[(wc * 4 + n) * 512 + lane * 8];
        }
        #pragma unroll
        for (int m = 0; m < 4; m++)
            #pragma unroll
            for (int n = 0; n < 4; n++) {
                accg[m][n] = __builtin_amdgcn_mfma_f32_16x16x32_bf16(af[m], gf[n], accg[m][n], 0, 0, 0);
                accu[m][n] = __builtin_amdgcn_mfma_f32_16x16x32_bf16(af[m], uf[n], accu[m][n], 0, 0, 0);
            }
        if constexpr (PREA) pa += 4096;
    }

    #pragma unroll
    for (int n = 0; n < 4; n++) {
        const int gcol = bn0 + wc * 64 + n * 16 + l15;
        const float sg = gs[gcol];
        const float su = us[gcol];
        const int c  = gcol >> 5;
        const int lp = ((gcol & 31) >> 3) * 16;
        const int e  = gcol & 7;
        #pragma unroll
        for (int m = 0; m < 4; m++) {
            const int rb = bm0 + wr * 64 + m * 16 + lq * 4;
            #pragma unroll
            for (int r = 0; r < 4; r++) {
                const int row = rb + r;
                float g = accg[m][n][r] * sg;
                float u = accu[m][n][r] * su;
                float hv = g * (1.0f / (1.0f + __expf(-g))) * u;
                const int t = row >> 7;
                const int f = (row >> 4) & 7;
                const int l = (row & 15) + lp;
                hid[(((size_t)t * KC2 + c) * 8 + f) * 512 + l * 8 + e] = f2bf(hv);
            }
        }
    }
}

__global__ __launch_bounds__(256, 2)
void k_gemm2_fb(const ushort_t* __restrict__ hid, const int* __restrict__ dt,
                const float* __restrict__ dsc, float* __restrict__ out)
{
    __shared__ ushort_t As[4096];
    __shared__ ushort_t Bs[4096];

    const int tid  = threadIdx.x;
    const int lane = tid & 63;
    const int wv   = tid >> 6;
    const int wr   = wv >> 1;
    const int wc   = wv & 1;
    const int l15  = lane & 15;
    const int lq   = lane >> 4;

    const int bid = blockIdx.x;
    const int bmt = bid & 63;
    const int bnt = bid >> 6;
    const int bm0 = bmt * 128;
    const int bn0 = bnt * 128;

    f32x4 acc[4][4] = {};
    const ushort_t* pa = hid + (size_t)bmt * KC2 * 4096;
    const int crow = tid >> 1;
    const int ccol = (tid & 1) * 16;

    for (int kc = 0; kc < KC2; kc++) {
        __syncthreads();
        GLDS16(pa + tid * 8,        &As[tid * 8]);
        GLDS16(pa + tid * 8 + 2048, &As[tid * 8 + 2048]);
        {
            const i32x4* dp = (const i32x4*)(dt + (size_t)(bn0 + crow) * FF_DIM + kc * 32 + ccol);
            i32x4 d0 = dp[0], d1 = dp[1], d2 = dp[2], d3 = dp[3];
            ds_write_frag(Bs, crow, ccol, pack_t8(d0, d1), pack_t8(d2, d3));
        }
        __syncthreads();

        bf16x8 af[4], bfr[4];
        #pragma unroll
        for (int m = 0; m < 4; m++)
            af[m] = *(const bf16x8*)&As[(wr * 4 + m) * 512 + lane * 8];
        #pragma unroll
        for (int n = 0; n < 4; n++)
            bfr[n] = *(const bf16x8*)&Bs[(wc * 4 + n) * 512 + lane * 8];
        #pragma unroll
        for (int m = 0; m < 4; m++)
            #pragma unroll
            for (int n = 0; n < 4; n++)
                acc[m][n] = __builtin_amdgcn_mfma_f32_16x16x32_bf16(af[m], bfr[n], acc[m][n], 0, 0, 0);
        pa += 4096;
    }

    #pragma unroll
    for (int n = 0; n < 4; n++) {
        const int gcol = bn0 + wc * 64 + n * 16 + l15;
        const float sd = dsc[gcol];
        #pragma unroll
        for (int m = 0; m < 4; m++) {
            const int grow = bm0 + wr * 64 + m * 16 + lq * 4;
            #pragma unroll
            for (int r = 0; r < 4; r++)
                out[(size_t)(grow + r) * H_DIM + gcol] = acc[m][n][r] * sd;
        }
    }
}

extern "C" void kernel_launch(void* const* d_in, const int* in_sizes, int n_in,
                              void* d_out, int out_size, void* d_ws, size_t ws_size,
                              hipStream_t stream) {
    const float* xf  = (const float*)d_in[0];
    const int*   gt  = (const int*)d_in[1];
    const int*   ut  = (const int*)d_in[2];
    const int*   dt  = (const int*)d_in[3];
    const float* gsc = (const float*)d_in[4];
    const float* usc = (const float*)d_in[5];
    const float* dsc = (const float*)d_in[6];
    float* out = (float*)d_out;

    const size_t HID_B = (size_t)M_TOK * FF_DIM * 2;   // 224 MiB hidden bf16 (frag order)
    const size_t XB_B  = (size_t)M_TOK * H_DIM * 2;    // 64 MiB  x bf16 (frag order)
    const size_t W_B   = (size_t)FF_DIM * H_DIM * 2;   // 112 MiB per weight bf16 (frag order)

    ushort_t* hid = (ushort_t*)d_ws;
    ushort_t* xbp = (ushort_t*)((char*)d_ws + HID_B);
    ushort_t* gbp = (ushort_t*)((char*)d_ws + HID_B + XB_B);
    ushort_t* ubp = gbp + (size_t)FF_DIM * H_DIM;
    ushort_t* dbp = ubp + (size_t)FF_DIM * H_DIM;

    const bool has_xb = ws_size >= HID_B + XB_B;
    const bool has_w  = ws_size >= HID_B + XB_B + 3 * W_B;

    if (has_xb) k_cvt_lds<H_DIM, false><<<4096, 256, 0, stream>>>(xf, xbp);
    if (has_w) {
        k_cvt_lds<H_DIM,  true><<<7168, 256, 0, stream>>>(gt, gbp);
        k_cvt_lds<H_DIM,  true><<<7168, 256, 0, stream>>>(ut, ubp);
        k_cvt_lds<FF_DIM, true><<<7168, 256, 0, stream>>>(dt, dbp);
    }

    if (has_w) {
        const int grid1 = 32 * 112;   // (M/256) * (FF/128), M-fastest
        const int grid2 = 32 * 16;    // (M/256) * (H/256)
        k_gemm1_8p<<<grid1, 512, 0, stream>>>(xbp, gbp, ubp, gsc, usc, hid);
        k_gemm2_8p<<<grid2, 512, 0, stream>>>(hid, dbp, dsc, out);
    } else {
        const int grid1 = 64 * 112;
        const int grid2 = 64 * 32;
        if (has_xb)
            k_gemm1_fb<true><<<grid1, 256, 0, stream>>>(nullptr, xbp, gt, ut, gsc, usc, hid);
        else
            k_gemm1_fb<false><<<grid1, 256, 0, stream>>>(xf, nullptr, gt, ut, gsc, usc, hid);
        k_gemm2_fb<<<grid2, 256, 0, stream>>>(hid, dt, dsc, out);
    }
}

// Round 4
// 1723.012 us; speedup vs baseline: 2.0792x; 1.3708x over previous
//
#include <hip/hip_runtime.h>
#include <stdint.h>

// Problem dims (fixed)
#define H_DIM   4096
#define FF_DIM  14336
#define M_TOK   8192     // B*S = 4*2048
#define KC1     (H_DIM / 32)    // 128 k-chunks (bf16 halves) for K=H
#define KC2     (FF_DIM / 32)   // 448 k-chunks (bf16 halves) for K=FF
#define KC1_8   (H_DIM / 64)    // 64 i8 chunks for K=H

typedef unsigned short ushort_t;
typedef __attribute__((ext_vector_type(8))) short  bf16x8;  // 8 bf16 (4 VGPRs)
typedef __attribute__((ext_vector_type(4))) float  f32x4;
typedef __attribute__((ext_vector_type(4))) int    i32x4;

// ---------- scalar converters ----------
__device__ __forceinline__ unsigned short f2bf(float f) {
    union { float f; uint32_t u; } v; v.f = f;
    uint32_t r = v.u + 0x7FFFu + ((v.u >> 16) & 1u);
    return (unsigned short)(r >> 16);
}
// ternary int32 {-1,0,1} -> exact bf16 bits
__device__ __forceinline__ unsigned short t2bf(int v) {
    unsigned int mag = (v & 1) ? 0x3F80u : 0u;
    unsigned int sgn = ((unsigned int)v >> 16) & 0x8000u;
    return (unsigned short)(mag | sgn);
}
__device__ __forceinline__ bf16x8 pack_f8(f32x4 a, f32x4 b) {
    bf16x8 o;
    o[0]=(short)f2bf(a[0]); o[1]=(short)f2bf(a[1]); o[2]=(short)f2bf(a[2]); o[3]=(short)f2bf(a[3]);
    o[4]=(short)f2bf(b[0]); o[5]=(short)f2bf(b[1]); o[6]=(short)f2bf(b[2]); o[7]=(short)f2bf(b[3]);
    return o;
}
__device__ __forceinline__ bf16x8 pack_t8(i32x4 a, i32x4 b) {
    bf16x8 o;
    o[0]=(short)t2bf(a[0]); o[1]=(short)t2bf(a[1]); o[2]=(short)t2bf(a[2]); o[3]=(short)t2bf(a[3]);
    o[4]=(short)t2bf(b[0]); o[5]=(short)t2bf(b[1]); o[6]=(short)t2bf(b[2]); o[7]=(short)t2bf(b[3]);
    return o;
}
__device__ __forceinline__ int pack4(int a, int b, int c, int d) {
    return (a & 255) | ((b & 255) << 8) | ((c & 255) << 16) | ((d & 255) << 24);
}

// async global->LDS, 16B per lane (dest = wave-uniform base + lane*16)
#define GLDS16(gp, lp) __builtin_amdgcn_global_load_lds( \
    (__attribute__((address_space(1))) void*)(gp),       \
    (__attribute__((address_space(3))) void*)(lp), 16, 0, 0)

#define WAITVM8 asm volatile("s_waitcnt vmcnt(8)" ::: "memory")
#define WAITVM4 asm volatile("s_waitcnt vmcnt(4)" ::: "memory")
#define WAITVM0 asm volatile("s_waitcnt vmcnt(0)" ::: "memory")
#define SBAR    asm volatile("s_barrier" ::: "memory")

// =====================================================================
// bf16 fragment-order layout (row-major [R][K]):
//   t=row/128, c=k/32, f=(row%128)/16, l=(row%16)+((k%32)/8)*16, e=k%8
//   flat = ((t*(K/32)+c)*8+f)*512 + l*8 + e     (per (t,c): 8 KiB)
// i8 fragment-order layout (K-chunks of 64):
//   t=row/128, c=k/64, f=(row%128)/16, l=(row%16)+16*((k%64)/16), j=k%16
//   byte = (t*(K/64)+c)*8192 + f*1024 + l*16 + j
//   Correct for ANY HW k-order because A and B use the same packing.
// =====================================================================

// ---------------- bf16 converter (LDS transpose, coalesced) ----------------
template<int K, bool TERN>
__global__ __launch_bounds__(256)
void k_cvt_lds(const void* __restrict__ inv, unsigned short* __restrict__ out) {
    constexpr int KC = K / 32;
    constexpr int CP = K / 64;
    __shared__ int sm[128][68];
    const int b   = blockIdx.x;
    const int t   = b / CP;
    const int cp  = b % CP;
    const int tid = threadIdx.x;
    const int rr  = tid >> 4;
    const int c4  = (tid & 15) * 4;
    const int k0  = cp * 64;

    const int* in = (const int*)inv;
    #pragma unroll
    for (int p = 0; p < 8; ++p) {
        const int row = p * 16 + rr;
        *(i32x4*)&sm[row][c4] = *(const i32x4*)(in + (size_t)(t * 128 + row) * K + k0 + c4);
    }
    __syncthreads();
    #pragma unroll
    for (int p = 0; p < 4; ++p) {
        const int idx = p * 256 + tid;
        const int cc  = idx >> 9;
        const int f   = (idx >> 6) & 7;
        const int l   = idx & 63;
        const int row = f * 16 + (l & 15);
        const int kl  = cc * 32 + (l >> 4) * 8;
        bf16x8 o;
        if (TERN) {
            i32x4 a = *(const i32x4*)&sm[row][kl];
            i32x4 bq = *(const i32x4*)&sm[row][kl + 4];
            o = pack_t8(a, bq);
        } else {
            f32x4 a = *(const f32x4*)&sm[row][kl];
            f32x4 bq = *(const f32x4*)&sm[row][kl + 4];
            o = pack_f8(a, bq);
        }
        *(bf16x8*)(out + (((size_t)t * KC + (cp * 2 + cc)) * 8 + f) * 512 + (size_t)l * 8) = o;
    }
}

// ---------------- per-token amax for x int8 quantization ----------------
__global__ __launch_bounds__(256)
void k_amax(const float* __restrict__ x, float* __restrict__ sx, float* __restrict__ rsx) {
    const int row  = blockIdx.x * 4 + (threadIdx.x >> 6);
    const int lane = threadIdx.x & 63;
    const f32x4* p = (const f32x4*)(x + (size_t)row * H_DIM);
    float m = 0.f;
    #pragma unroll 4
    for (int i = lane; i < H_DIM / 4; i += 64) {
        f32x4 v = p[i];
        m = fmaxf(m, fmaxf(fmaxf(fabsf(v[0]), fabsf(v[1])), fmaxf(fabsf(v[2]), fabsf(v[3]))));
    }
    #pragma unroll
    for (int o = 32; o; o >>= 1) m = fmaxf(m, __shfl_xor(m, o, 64));
    if (lane == 0) {
        sx[row]  = m * (1.f / 127.f);
        rsx[row] = m > 0.f ? 127.f / m : 0.f;
    }
}

// ---------------- i8 frag converter (x quantized / ternary truncated) ----------------
template<int K, bool TERN>
__global__ __launch_bounds__(256)
void k_cvt_i8(const void* __restrict__ inv, const float* __restrict__ rsx,
              char* __restrict__ out) {
    constexpr int CP = K / 64;
    __shared__ int sm[128][68];
    const int b   = blockIdx.x;
    const int t   = b / CP;
    const int cp  = b % CP;
    const int tid = threadIdx.x;
    const int rr  = tid >> 4;
    const int c4  = (tid & 15) * 4;

    const int* in = (const int*)inv;
    #pragma unroll
    for (int p = 0; p < 8; ++p) {
        const int row = p * 16 + rr;
        *(i32x4*)&sm[row][c4] = *(const i32x4*)(in + (size_t)(t * 128 + row) * K + cp * 64 + c4);
    }
    __syncthreads();
    #pragma unroll
    for (int p = 0; p < 2; ++p) {
        const int pos = p * 256 + tid;          // 0..511
        const int f = pos >> 6, l = pos & 63;
        const int row = f * 16 + (l & 15);
        const int kb  = (l >> 4) * 16;
        i32x4 o;
        if constexpr (TERN) {
            #pragma unroll
            for (int q = 0; q < 4; ++q)
                o[q] = pack4(sm[row][kb + q * 4], sm[row][kb + q * 4 + 1],
                             sm[row][kb + q * 4 + 2], sm[row][kb + q * 4 + 3]);
        } else {
            const float rs = rsx[t * 128 + row];
            #pragma unroll
            for (int q = 0; q < 4; ++q) {
                const float* fp = (const float*)&sm[row][kb + q * 4];
                o[q] = pack4(__float2int_rn(fp[0] * rs), __float2int_rn(fp[1] * rs),
                             __float2int_rn(fp[2] * rs), __float2int_rn(fp[3] * rs));
            }
        }
        *(i32x4*)(out + ((size_t)t * CP + cp) * 8192 + f * 1024 + (size_t)l * 16) = o;
    }
}

// ---------------- GEMM1 int8 8-phase: hidden = silu(x@g^T*sx*gs)*(x@u^T*sx*us) ------
// 256M x (128 gate + 128 up) tile, 8 waves (4Mx2N), K-chunks of 64.
// LDS: 4 slots x 32KB (A0 8K, A1 8K, G 8K, U 8K). Depth-3 prefetch, vmcnt(8).
__global__ __launch_bounds__(512, 2)
void k_gemm1_i8(const char* __restrict__ xq,
                const char* __restrict__ gq, const char* __restrict__ uq,
                const float* __restrict__ sxp,
                const float* __restrict__ gs, const float* __restrict__ us,
                ushort_t* __restrict__ hid)
{
    __shared__ char lds[131072];   // 128 KiB
    const int tid  = threadIdx.x;
    const int lane = tid & 63;
    const int wv   = tid >> 6;
    const int wr   = wv >> 1;          // 0..3 (M)
    const int wc   = wv & 1;           // 0..1 (N)
    const int l15  = lane & 15;
    const int lq   = lane >> 4;

    const int bid = blockIdx.x;
    const int bmt = bid & 31;          // 32 m-tiles of 256 (M-fastest)
    const int bnt = bid >> 5;          // 112 ff-tiles of 128

    const char* xa0 = xq + (size_t)(bmt * 2)     * KC1_8 * 8192;
    const char* xa1 = xq + (size_t)(bmt * 2 + 1) * KC1_8 * 8192;
    const char* gbb = gq + (size_t)bnt * KC1_8 * 8192;
    const char* ubb = uq + (size_t)bnt * KC1_8 * 8192;

    i32x4 accg[4][4] = {};
    i32x4 accu[4][4] = {};

    // prologue: stage chunks 0,1,2
    #pragma unroll
    for (int h = 0; h < 3; ++h) {
        char* sl = lds + h * 32768;
        GLDS16(xa0 + (size_t)h * 8192 + tid * 16, sl + tid * 16);
        GLDS16(xa1 + (size_t)h * 8192 + tid * 16, sl + 8192 + tid * 16);
        GLDS16(gbb + (size_t)h * 8192 + tid * 16, sl + 16384 + tid * 16);
        GLDS16(ubb + (size_t)h * 8192 + tid * 16, sl + 24576 + tid * 16);
    }

#define G1I(WAITOP, DO_ISSUE)                                                      \
  {                                                                                \
    char* slot = lds + (H & 3) * 32768;                                            \
    const char* Ab = slot + (wr >> 1) * 8192 + ((wr & 1) * 4) * 1024 + lane * 16;  \
    const char* Gb = slot + 16384 + (wc * 4) * 1024 + lane * 16;                   \
    const char* Ub = slot + 24576 + (wc * 4) * 1024 + lane * 16;                   \
    WAITOP;                                                                        \
    SBAR;                                                                          \
    i32x4 af[4], gf[4], uf[4];                                                     \
    _Pragma("unroll")                                                              \
    for (int m = 0; m < 4; m++) af[m] = *(const i32x4*)(Ab + m * 1024);            \
    _Pragma("unroll")                                                              \
    for (int n = 0; n < 4; n++) gf[n] = *(const i32x4*)(Gb + n * 1024);            \
    if (DO_ISSUE) {                                                                \
      const int Hp = H + 3;                                                        \
      char* sp = lds + (Hp & 3) * 32768;                                           \
      GLDS16(xa0 + (size_t)Hp * 8192 + tid * 16, sp + tid * 16);                   \
      GLDS16(xa1 + (size_t)Hp * 8192 + tid * 16, sp + 8192 + tid * 16);            \
    }                                                                              \
    __builtin_amdgcn_s_setprio(1);                                                 \
    _Pragma("unroll")                                                              \
    for (int m = 0; m < 4; m++)                                                    \
      _Pragma("unroll")                                                            \
      for (int n = 0; n < 4; n++)                                                  \
        accg[m][n] = __builtin_amdgcn_mfma_i32_16x16x64_i8(af[m], gf[n], accg[m][n], 0, 0, 0); \
    __builtin_amdgcn_s_setprio(0);                                                 \
    SBAR;                                                                          \
    _Pragma("unroll")                                                              \
    for (int n = 0; n < 4; n++) uf[n] = *(const i32x4*)(Ub + n * 1024);            \
    if (DO_ISSUE) {                                                                \
      const int Hp = H + 3;                                                        \
      char* sp = lds + (Hp & 3) * 32768;                                           \
      GLDS16(gbb + (size_t)Hp * 8192 + tid * 16, sp + 16384 + tid * 16);           \
      GLDS16(ubb + (size_t)Hp * 8192 + tid * 16, sp + 24576 + tid * 16);           \
    }                                                                              \
    __builtin_amdgcn_s_setprio(1);                                                 \
    _Pragma("unroll")                                                              \
    for (int m = 0; m < 4; m++)                                                    \
      _Pragma("unroll")                                                            \
      for (int n = 0; n < 4; n++)                                                  \
        accu[m][n] = __builtin_amdgcn_mfma_i32_16x16x64_i8(af[m], uf[n], accu[m][n], 0, 0, 0); \
    __builtin_amdgcn_s_setprio(0);                                                 \
  }

    int H = 0;
    for (; H < KC1_8 - 3; ++H) G1I(WAITVM8, 1);
    G1I(WAITVM8, 0); ++H;
    G1I(WAITVM4, 0); ++H;
    G1I(WAITVM0, 0);
#undef G1I

    // epilogue: dequant (i32 * sx * scale), silu(g)*u, store bf16 hidden in frag order
    const int bm0 = bmt * 256;
    const int bn0 = bnt * 128;
    float sxv[4][4];
    #pragma unroll
    for (int m = 0; m < 4; m++) {
        const int rb = bm0 + wr * 64 + m * 16 + lq * 4;
        #pragma unroll
        for (int r = 0; r < 4; r++) sxv[m][r] = sxp[rb + r];
    }
    #pragma unroll
    for (int n = 0; n < 4; n++) {
        const int gcol = bn0 + wc * 64 + n * 16 + l15;   // k index for gemm2
        const float sg = gs[gcol];
        const float su = us[gcol];
        const int c  = gcol >> 5;
        const int lp = ((gcol & 31) >> 3) * 16;
        const int e  = gcol & 7;
        #pragma unroll
        for (int m = 0; m < 4; m++) {
            const int rb = bm0 + wr * 64 + m * 16 + lq * 4;
            #pragma unroll
            for (int r = 0; r < 4; r++) {
                const int row = rb + r;
                float g = (float)accg[m][n][r] * (sxv[m][r] * sg);
                float u = (float)accu[m][n][r] * (sxv[m][r] * su);
                float hv = g * (1.0f / (1.0f + __expf(-g))) * u;
                const int t = row >> 7;
                const int f = (row >> 4) & 7;
                const int l = (row & 15) + lp;
                hid[(((size_t)t * KC2 + c) * 8 + f) * 512 + l * 8 + e] = f2bf(hv);
            }
        }
    }
}

// ---------------- GEMM2 8-phase bf16: out = (hidden @ down^T) * ds ----------------
__global__ __launch_bounds__(512, 2)
void k_gemm2_8p(const ushort_t* __restrict__ hid, const ushort_t* __restrict__ db,
                const float* __restrict__ dsc, float* __restrict__ out)
{
    __shared__ ushort_t lds[65536];
    const int tid  = threadIdx.x;
    const int lane = tid & 63;
    const int wv   = tid >> 6;
    const int wr   = wv >> 2;
    const int wc   = wv & 3;
    const int l15  = lane & 15;
    const int lq   = lane >> 4;

    const int bid = blockIdx.x;
    const int bmt = bid & 31;
    const int bnt = bid >> 5;

    const ushort_t* ha0 = hid + ((size_t)(bmt * 2)     * KC2) * 4096;
    const ushort_t* ha1 = hid + ((size_t)(bmt * 2 + 1) * KC2) * 4096;
    const ushort_t* db0 = db  + ((size_t)(bnt * 2)     * KC2) * 4096;
    const ushort_t* db1 = db  + ((size_t)(bnt * 2 + 1) * KC2) * 4096;

    f32x4 acc[8][4] = {};

    #pragma unroll
    for (int h = 0; h < 3; ++h) {
        ushort_t* sl = lds + h * 16384;
        GLDS16(ha0 + (size_t)h * 4096 + tid * 8, sl + tid * 8);
        GLDS16(ha1 + (size_t)h * 4096 + tid * 8, sl + 4096 + tid * 8);
        GLDS16(db0 + (size_t)h * 4096 + tid * 8, sl + 8192 + tid * 8);
        GLDS16(db1 + (size_t)h * 4096 + tid * 8, sl + 12288 + tid * 8);
    }

#define G2_HALF(WAITOP, DO_ISSUE)                                                  \
  {                                                                                \
    ushort_t* slot = lds + (H & 3) * 16384;                                        \
    const ushort_t* Ab = slot + wr * 4096 + lane * 8;                              \
    const ushort_t* Bb = slot + 8192 + (wc >> 1) * 4096 + ((wc & 1) * 4) * 512 + lane * 8; \
    WAITOP;                                                                        \
    SBAR;                                                                          \
    bf16x8 af[4], bfv[4];                                                          \
    _Pragma("unroll")                                                              \
    for (int m = 0; m < 4; m++) af[m] = *(const bf16x8*)(Ab + m * 512);            \
    _Pragma("unroll")                                                              \
    for (int n = 0; n < 4; n++) bfv[n] = *(const bf16x8*)(Bb + n * 512);           \
    if (DO_ISSUE) {                                                                \
      const int Hp = H + 3;                                                        \
      ushort_t* sp = lds + (Hp & 3) * 16384;                                       \
      GLDS16(ha0 + (size_t)Hp * 4096 + tid * 8, sp + tid * 8);                     \
      GLDS16(ha1 + (size_t)Hp * 4096 + tid * 8, sp + 4096 + tid * 8);              \
    }                                                                              \
    __builtin_amdgcn_s_setprio(1);                                                 \
    _Pragma("unroll")                                                              \
    for (int m = 0; m < 4; m++)                                                    \
      _Pragma("unroll")                                                            \
      for (int n = 0; n < 4; n++)                                                  \
        acc[m][n] = __builtin_amdgcn_mfma_f32_16x16x32_bf16(af[m], bfv[n], acc[m][n], 0, 0, 0); \
    __builtin_amdgcn_s_setprio(0);                                                 \
    SBAR;                                                                          \
    bf16x8 af2[4];                                                                 \
    _Pragma("unroll")                                                              \
    for (int m = 0; m < 4; m++) af2[m] = *(const bf16x8*)(Ab + (4 + m) * 512);     \
    if (DO_ISSUE) {                                                                \
      const int Hp = H + 3;                                                        \
      ushort_t* sp = lds + (Hp & 3) * 16384;                                       \
      GLDS16(db0 + (size_t)Hp * 4096 + tid * 8, sp + 8192 + tid * 8);              \
      GLDS16(db1 + (size_t)Hp * 4096 + tid * 8, sp + 12288 + tid * 8);             \
    }                                                                              \
    __builtin_amdgcn_s_setprio(1);                                                 \
    _Pragma("unroll")                                                              \
    for (int m = 0; m < 4; m++)                                                    \
      _Pragma("unroll")                                                            \
      for (int n = 0; n < 4; n++)                                                  \
        acc[4 + m][n] = __builtin_amdgcn_mfma_f32_16x16x32_bf16(af2[m], bfv[n], acc[4 + m][n], 0, 0, 0); \
    __builtin_amdgcn_s_setprio(0);                                                 \
  }

    int H = 0;
    for (; H < KC2 - 3; ++H) G2_HALF(WAITVM8, 1);
    G2_HALF(WAITVM8, 0); ++H;
    G2_HALF(WAITVM4, 0); ++H;
    G2_HALF(WAITVM0, 0);
#undef G2_HALF

    const int bm0 = bmt * 256;
    const int bn0 = bnt * 256;
    #pragma unroll
    for (int n = 0; n < 4; n++) {
        const int gcol = bn0 + wc * 64 + n * 16 + l15;
        const float sd = dsc[gcol];
        #pragma unroll
        for (int m = 0; m < 8; m++) {
            const int grow = bm0 + wr * 128 + m * 16 + lq * 4;
            #pragma unroll
            for (int r = 0; r < 4; r++)
                out[(size_t)(grow + r) * H_DIM + gcol] = acc[m][n][r] * sd;
        }
    }
}

// ================= fallback (small ws) — R2 structure, known good =================
__device__ __forceinline__ void ds_write_frag(ushort_t* buf, int crow, int ccol,
                                              bf16x8 lo, bf16x8 hi) {
    int f  = crow >> 4;
    int la = (crow & 15) + (((ccol)     & 31) >> 3) * 16;
    int lb = (crow & 15) + (((ccol + 8) & 31) >> 3) * 16;
    *(bf16x8*)&buf[f * 512 + la * 8] = lo;
    *(bf16x8*)&buf[f * 512 + lb * 8] = hi;
}

template<bool PREA>
__global__ __launch_bounds__(256, 2)
void k_gemm1_fb(const float* __restrict__ xf, const ushort_t* __restrict__ xb,
                const int* __restrict__ gt, const int* __restrict__ ut,
                const float* __restrict__ gs, const float* __restrict__ us,
                ushort_t* __restrict__ hid)
{
    __shared__ ushort_t As[4096];
    __shared__ ushort_t Gs[4096];
    __shared__ ushort_t Us[4096];

    const int tid  = threadIdx.x;
    const int lane = tid & 63;
    const int wv   = tid >> 6;
    const int wr   = wv >> 1;
    const int wc   = wv & 1;
    const int l15  = lane & 15;
    const int lq   = lane >> 4;

    const int bid = blockIdx.x;
    const int bmt = bid & 63;
    const int bnt = bid >> 6;
    const int bm0 = bmt * 128;
    const int bn0 = bnt * 128;

    f32x4 accg[4][4] = {};
    f32x4 accu[4][4] = {};

    const ushort_t* pa = PREA ? xb + (size_t)bmt * KC1 * 4096 : nullptr;
    const int crow = tid >> 1;
    const int ccol = (tid & 1) * 16;

    for (int kc = 0; kc < KC1; kc++) {
        __syncthreads();
        const int k0 = kc * 32;
        if constexpr (PREA) {
            GLDS16(pa + tid * 8,        &As[tid * 8]);
            GLDS16(pa + tid * 8 + 2048, &As[tid * 8 + 2048]);
        } else {
            const float* xa = xf + (size_t)(bm0 + crow) * H_DIM + k0 + ccol;
            f32x4 a0 = ((const f32x4*)xa)[0], a1 = ((const f32x4*)xa)[1];
            f32x4 a2 = ((const f32x4*)xa)[2], a3 = ((const f32x4*)xa)[3];
            ds_write_frag(As, crow, ccol, pack_f8(a0, a1), pack_f8(a2, a3));
        }
        {
            const size_t wo = (size_t)(bn0 + crow) * H_DIM + k0 + ccol;
            const i32x4* gp = (const i32x4*)(gt + wo);
            i32x4 g0 = gp[0], g1 = gp[1], g2 = gp[2], g3 = gp[3];
            ds_write_frag(Gs, crow, ccol, pack_t8(g0, g1), pack_t8(g2, g3));
            const i32x4* up = (const i32x4*)(ut + wo);
            i32x4 u0 = up[0], u1 = up[1], u2 = up[2], u3 = up[3];
            ds_write_frag(Us, crow, ccol, pack_t8(u0, u1), pack_t8(u2, u3));
        }
        __syncthreads();

        bf16x8 af[4], gf[4], uf[4];
        #pragma unroll
        for (int m = 0; m < 4; m++)
            af[m] = *(const bf16x8*)&As[(wr * 4 + m) * 512 + lane * 8];
        #pragma unroll
        for (int n = 0; n < 4; n++) {
            gf[n] = *(const bf16x8*)&Gs[(wc * 4 + n) * 512 + lane * 8];
            uf[n] = *(const bf16x8*)&Us[(wc * 4 + n) * 512 + lane * 8];
        }
        #pragma unroll
        for (int m = 0; m < 4; m++)
            #pragma unroll
            for (int n = 0; n < 4; n++) {
                accg[m][n] = __builtin_amdgcn_mfma_f32_16x16x32_bf16(af[m], gf[n], accg[m][n], 0, 0, 0);
                accu[m][n] = __builtin_amdgcn_mfma_f32_16x16x32_bf16(af[m], uf[n], accu[m][n], 0, 0, 0);
            }
        if constexpr (PREA) pa += 4096;
    }

    #pragma unroll
    for (int n = 0; n < 4; n++) {
        const int gcol = bn0 + wc * 64 + n * 16 + l15;
        const float sg = gs[gcol];
        const float su = us[gcol];
        const int c  = gcol >> 5;
        const int lp = ((gcol & 31) >> 3) * 16;
        const int e  = gcol & 7;
        #pragma unroll
        for (int m = 0; m < 4; m++) {
            const int rb = bm0 + wr * 64 + m * 16 + lq * 4;
            #pragma unroll
            for (int r = 0; r < 4; r++) {
                const int row = rb + r;
                float g = accg[m][n][r] * sg;
                float u = accu[m][n][r] * su;
                float hv = g * (1.0f / (1.0f + __expf(-g))) * u;
                const int t = row >> 7;
                const int f = (row >> 4) & 7;
                const int l = (row & 15) + lp;
                hid[(((size_t)t * KC2 + c) * 8 + f) * 512 + l * 8 + e] = f2bf(hv);
            }
        }
    }
}

__global__ __launch_bounds__(256, 2)
void k_gemm2_fb(const ushort_t* __restrict__ hid, const int* __restrict__ dt,
                const float* __restrict__ dsc, float* __restrict__ out)
{
    __shared__ ushort_t As[4096];
    __shared__ ushort_t Bs[4096];

    const int tid  = threadIdx.x;
    const int lane = tid & 63;
    const int wv   = tid >> 6;
    const int wr   = wv >> 1;
    const int wc   = wv & 1;
    const int l15  = lane & 15;
    const int lq   = lane >> 4;

    const int bid = blockIdx.x;
    const int bmt = bid & 63;
    const int bnt = bid >> 6;
    const int bm0 = bmt * 128;
    const int bn0 = bnt * 128;

    f32x4 acc[4][4] = {};
    const ushort_t* pa = hid + (size_t)bmt * KC2 * 4096;
    const int crow = tid >> 1;
    const int ccol = (tid & 1) * 16;

    for (int kc = 0; kc < KC2; kc++) {
        __syncthreads();
        GLDS16(pa + tid * 8,        &As[tid * 8]);
        GLDS16(pa + tid * 8 + 2048, &As[tid * 8 + 2048]);
        {
            const i32x4* dp = (const i32x4*)(dt + (size_t)(bn0 + crow) * FF_DIM + kc * 32 + ccol);
            i32x4 d0 = dp[0], d1 = dp[1], d2 = dp[2], d3 = dp[3];
            ds_write_frag(Bs, crow, ccol, pack_t8(d0, d1), pack_t8(d2, d3));
        }
        __syncthreads();

        bf16x8 af[4], bfr[4];
        #pragma unroll
        for (int m = 0; m < 4; m++)
            af[m] = *(const bf16x8*)&As[(wr * 4 + m) * 512 + lane * 8];
        #pragma unroll
        for (int n = 0; n < 4; n++)
            bfr[n] = *(const bf16x8*)&Bs[(wc * 4 + n) * 512 + lane * 8];
        #pragma unroll
        for (int m = 0; m < 4; m++)
            #pragma unroll
            for (int n = 0; n < 4; n++)
                acc[m][n] = __builtin_amdgcn_mfma_f32_16x16x32_bf16(af[m], bfr[n], acc[m][n], 0, 0, 0);
        pa += 4096;
    }

    #pragma unroll
    for (int n = 0; n < 4; n++) {
        const int gcol = bn0 + wc * 64 + n * 16 + l15;
        const float sd = dsc[gcol];
        #pragma unroll
        for (int m = 0; m < 4; m++) {
            const int grow = bm0 + wr * 64 + m * 16 + lq * 4;
            #pragma unroll
            for (int r = 0; r < 4; r++)
                out[(size_t)(grow + r) * H_DIM + gcol] = acc[m][n][r] * sd;
        }
    }
}

extern "C" void kernel_launch(void* const* d_in, const int* in_sizes, int n_in,
                              void* d_out, int out_size, void* d_ws, size_t ws_size,
                              hipStream_t stream) {
    const float* xf  = (const float*)d_in[0];
    const int*   gt  = (const int*)d_in[1];
    const int*   ut  = (const int*)d_in[2];
    const int*   dt  = (const int*)d_in[3];
    const float* gsc = (const float*)d_in[4];
    const float* usc = (const float*)d_in[5];
    const float* dsc = (const float*)d_in[6];
    float* out = (float*)d_out;

    const size_t HID_B = (size_t)M_TOK * FF_DIM * 2;   // 224 MiB hidden bf16 frag
    const size_t DB_B  = (size_t)FF_DIM * H_DIM * 2;   // 112 MiB down bf16 frag
    const size_t G8_B  = (size_t)FF_DIM * H_DIM;       // 56 MiB gate i8 frag
    const size_t U8_B  = (size_t)FF_DIM * H_DIM;       // 56 MiB up i8 frag
    const size_t X8_B  = (size_t)M_TOK * H_DIM;        // 32 MiB x i8 frag
    const size_t SX_B  = (size_t)M_TOK * 4;            // 32 KiB
    const size_t XB_B  = (size_t)M_TOK * H_DIM * 2;    // 64 MiB x bf16 frag (fallback)

    char* base = (char*)d_ws;
    ushort_t* hid = (ushort_t*)base;
    ushort_t* dbp = (ushort_t*)(base + HID_B);
    char*     g8  = base + HID_B + DB_B;
    char*     u8  = g8 + G8_B;
    char*     x8  = u8 + U8_B;
    float*    sxp = (float*)(x8 + X8_B);
    float*    rsx = sxp + M_TOK;
    ushort_t* xbp = (ushort_t*)(base + HID_B);         // fallback only (excl. with dbp)

    const bool has_w  = ws_size >= HID_B + DB_B + G8_B + U8_B + X8_B + 2 * SX_B;
    const bool has_xb = ws_size >= HID_B + XB_B;

    if (has_w) {
        k_amax<<<M_TOK / 4, 256, 0, stream>>>(xf, sxp, rsx);
        k_cvt_i8<H_DIM,  false><<<(M_TOK / 128) * (H_DIM / 64), 256, 0, stream>>>(xf, rsx, x8);
        k_cvt_i8<H_DIM,  true ><<<(FF_DIM / 128) * (H_DIM / 64), 256, 0, stream>>>(gt, nullptr, g8);
        k_cvt_i8<H_DIM,  true ><<<(FF_DIM / 128) * (H_DIM / 64), 256, 0, stream>>>(ut, nullptr, u8);
        k_cvt_lds<FF_DIM, true><<<(H_DIM / 128) * (FF_DIM / 64), 256, 0, stream>>>(dt, dbp);

        k_gemm1_i8<<<32 * 112, 512, 0, stream>>>(x8, g8, u8, sxp, gsc, usc, hid);
        k_gemm2_8p<<<32 * 16, 512, 0, stream>>>(hid, dbp, dsc, out);
    } else {
        const int grid1 = 64 * 112;
        const int grid2 = 64 * 32;
        if (has_xb) {
            k_cvt_lds<H_DIM, false><<<(M_TOK / 128) * (H_DIM / 64), 256, 0, stream>>>(xf, xbp);
            k_gemm1_fb<true><<<grid1, 256, 0, stream>>>(nullptr, xbp, gt, ut, gsc, usc, hid);
        } else {
            k_gemm1_fb<false><<<grid1, 256, 0, stream>>>(xf, nullptr, gt, ut, gsc, usc, hid);
        }
        k_gemm2_fb<<<grid2, 256, 0, stream>>>(hid, dt, dsc, out);
    }
}